// Round 2
// 78.896 us; speedup vs baseline: 1.0209x; 1.0209x over previous
//
#include <hip/hip_runtime.h>

#define NB     32
#define NATOM  48
#define NGRID  128
#define KT     8                          /* grid points per block */
#define NTHR   768                        /* 12 waves: thread = (n, kk, h) */

#define MBTR_ELEMS (NB*16*NGRID)          /* 65536 */
#define DIV_PER_B  (16*NGRID*NATOM*3)     /* 294912 */
#define PANE       (NGRID*NATOM*3)        /* 18432 floats per (e1,e2) pane */
#define MSTRIDE    49                     /* padded n-stride for M table */

// R9: resubmit of R8 (previous round was an MI355X container infra failure,
// not a kernel result — audited: no divergent barriers, no OOB, no write
// races, loop bounds all <=48).
// R8: OCCUPANCY SPLIT. Evidence: timed graph = 256MiB workspace re-poison
// (~44us @6.1TB/s, the recurring 262144KB fills) + mbtr_fused (<43us, absent
// from top-5) => kernel ~36us. Kernel roofline: 38.8MB writes ~6.5us, phase-1
// VALU ~3us => ~9% issue util & ~17% write BW => latency-bound. Occupancy is
// GRID-CAPPED: 512 blocks x 6 waves = 12 waves/CU. Fix: split the species
// dimension across two thread-halves (h owns elements {2h,2h+1}): 2x waves
// (24/CU) and half the serial pair loop per thread (48 -> ~24 iters).
// Pane (e1,e2) write ownership (exactly one writer per output, static-e
// indexing preserved per R4 lesson):
//   e1==e2: owner = half(e1); value = (zn==e1) ? 2*A[e1] : 0
//   e1!=e2: zn==e1 -> owner half(e2) writes A[e2]; zn==e2 -> owner half(e1)
//           writes A[e1]; else h==0 writes 0.
// Everything else (sorted-position inner loop, register-direct div stores,
// M-table reduction) identical to R5/R7 best.
__global__ __launch_bounds__(NTHR, 6)
void mbtr_fused(const float* __restrict__ r, const int* __restrict__ z,
                const float* __restrict__ grid, float* __restrict__ out)
{
    const int kt = blockIdx.x, b = blockIdx.y, t = threadIdx.x;
    const int k0 = kt * KT;

    __shared__ float4 pos_s[NATOM + 1];   /* species-sorted; +1 prefetch pad */
    __shared__ int    zl[NATOM];
    __shared__ int    soff_s[5];
    __shared__ float  znpos[NATOM * 3];   /* unsorted positions for rn */
    __shared__ float  Mrec[KT * 4 * MSTRIDE];   /* [kk][e][49] */

    // ---- setup: wave 0 loads atoms, scatters them species-sorted ----
    if (t < 64) {
        const bool isatom = (t < NATOM);
        int myz = 999;
        float rx = 0.f, ry = 0.f, rz = 0.f;
        if (isatom) {
            myz = z[t];
            zl[t] = myz;
            const float* rp = r + ((size_t)b * NATOM + t) * 3;
            rx = rp[0]; ry = rp[1]; rz = rp[2];
            znpos[t * 3 + 0] = rx; znpos[t * 3 + 1] = ry; znpos[t * 3 + 2] = rz;
        }
        const unsigned long long m0 = __ballot(myz == 0);
        const unsigned long long m1 = __ballot(myz == 1);
        const unsigned long long m2 = __ballot(myz == 2);
        const unsigned long long m3 = __ballot(myz == 3);
        const int c0 = __popcll(m0), c1 = __popcll(m1), c2 = __popcll(m2);
        if (isatom) {
            const unsigned long long mm = (myz == 0) ? m0 : (myz == 1) ? m1
                                        : (myz == 2) ? m2 : m3;
            const int base = (myz == 0) ? 0 : (myz == 1) ? c0
                           : (myz == 2) ? c0 + c1 : c0 + c1 + c2;
            const int rank = __popcll(mm & ((1ull << t) - 1ull));
            pos_s[base + rank] = make_float4(rx, ry, rz, (float)t);
        }
        if (t == 0) {
            soff_s[0] = 0; soff_s[1] = c0; soff_s[2] = c0 + c1;
            soff_s[3] = c0 + c1 + c2; soff_s[4] = NATOM;
            pos_s[NATOM] = make_float4(0.f, 0.f, 0.f, -1.f);  // prefetch pad
        }
    }
    __syncthreads();

    // ---- phase 1: thread = (n, kk, h); h owns species {2h, 2h+1} ----
    const int n  = t % NATOM;
    const int kk = (t / NATOM) & (KT - 1);  // 0..7
    const int h  = t / (NATOM * KT);        // 0 or 1
    const float dx   = grid[1] - grid[0];
    const float coef = dx * 7.9788456080286535f;     // dx*20/sqrt(2pi)
    const float mlc  = -__log2f(coef);
    const float isc  = 16.986436005760382f;          // 20*sqrt(log2e/2)
    const float tBc  = 23.548200452219559f;          // 20/sqrt(log2e/2)
    const float l2e  = 1.4426950408889634f;
    const float gk   = grid[k0 + kk] * isc;
    const float nf   = (float)n;

    float A[2][3] = {{0.f}};
    float M[2]    = {0.f, 0.f};
    const float rnx = znpos[n * 3 + 0];
    const float rny = znpos[n * 3 + 1];
    const float rnz = znpos[n * 3 + 2];
    const int   zn  = zl[n];
    const int so0 = soff_s[2 * h];
    const int so1 = soff_s[2 * h + 1];
    const int so2 = soff_s[2 * h + 2];

#define SEG_LOOP(LO, HI, J)                                                 \
    _Pragma("unroll 4")                                                     \
    for (int i = (LO); i < (HI); ++i) {                                     \
        const float4 rm = pos_s[i];     /* static-address broadcast read */ \
        const float ddx = rnx - rm.x, ddy = rny - rm.y, ddz = rnz - rm.z;   \
        float d2 = ddx*ddx + ddy*ddy + ddz*ddz;                             \
        const bool self = (rm.w == nf);                                     \
        d2 = self ? 1.0f : d2;                        /* rsq NaN guard */   \
        const float gf  = __builtin_amdgcn_rsqf(d2);  /* 1/d */             \
        const float c1  = gf * isc;                                         \
        const float d   = d2 * gf;                                          \
        float base = fmaf(d, l2e, mlc);               /* wf & coef folded */\
        base = self ? 1e30f : base;                   /* kill self pair */  \
        const float bq  = (gf * gf) * tBc;                                  \
        const float tt  = gk - c1;                                          \
        const float ex  = exp2f(-fmaf(tt, tt, base)); /* coef*wf*gv */      \
        M[J] += ex;                                                         \
        const float p   = ex * fmaf(tt, bq, 1.0f);                          \
        A[J][0] = fmaf(-p, gf * ddx, A[J][0]);                              \
        A[J][1] = fmaf(-p, gf * ddy, A[J][1]);                              \
        A[J][2] = fmaf(-p, gf * ddz, A[J][2]);                              \
    }

    SEG_LOOP(so0, so1, 0)
    SEG_LOOP(so1, so2, 1)
#undef SEG_LOOP

    {   // M table to LDS: this half's two element rows
        float* mr = Mrec + kk * (4 * MSTRIDE) + n;
        mr[(2 * h + 0) * MSTRIDE] = M[0];
        mr[(2 * h + 1) * MSTRIDE] = M[1];
    }

    // ---- phase 2a: div writes straight from registers (owner rule) ----
    float* basep = out + MBTR_ELEMS + (size_t)b * DIV_PER_B
                 + (size_t)(k0 + kk) * 144 + n * 3;
    #pragma unroll
    for (int e1 = 0; e1 < 4; ++e1) {
        #pragma unroll
        for (int e2 = 0; e2 < 4; ++e2) {
            float3 v; bool w;
            if (e1 == e2) {
                w = ((e1 >> 1) == h);
                const bool s = (zn == e1);
                v.x = s ? 2.f * A[e1 & 1][0] : 0.f;
                v.y = s ? 2.f * A[e1 & 1][1] : 0.f;
                v.z = s ? 2.f * A[e1 & 1][2] : 0.f;
            } else {
                const bool o2 = ((e2 >> 1) == h) & (zn == e1); // -> A[e2]
                const bool o1 = ((e1 >> 1) == h) & (zn == e2); // -> A[e1]
                const bool oz = (h == 0) & (zn != e1) & (zn != e2);
                w = o2 | o1 | oz;
                v.x = o2 ? A[e2 & 1][0] : (o1 ? A[e1 & 1][0] : 0.f);
                v.y = o2 ? A[e2 & 1][1] : (o1 ? A[e1 & 1][1] : 0.f);
                v.z = o2 ? A[e2 & 1][2] : (o1 ? A[e1 & 1][2] : 0.f);
            }
            if (w)
                *(float3*)(basep + (e1 * 4 + e2) * PANE) = v;
        }
    }

    __syncthreads();

    // ---- phase 2b: mbtr reduction (threads 0..127: one (pane,kk) each) ----
    if (t < 128) {
        const int mpane = t >> 3, mkk = t & 7;
        const int me1 = mpane >> 2, me2 = mpane & 3;
        const float* tr2 = Mrec + mkk * (4 * MSTRIDE) + me2 * MSTRIDE;
        float s = 0.f;
        #pragma unroll
        for (int nn = 0; nn < NATOM; ++nn)
            s += (zl[nn] == me1) ? tr2[nn] : 0.f;
        out[(size_t)b * 2048 + mpane * NGRID + k0 + mkk] = s;
    }
}

extern "C" void kernel_launch(void* const* d_in, const int* in_sizes, int n_in,
                              void* d_out, int out_size, void* d_ws, size_t ws_size,
                              hipStream_t stream)
{
    const float* r    = (const float*)d_in[0];
    const int*   z    = (const int*)  d_in[1];
    const float* grid = (const float*)d_in[2];
    float* out = (float*)d_out;
    (void)d_ws; (void)ws_size;

    mbtr_fused<<<dim3(NGRID / KT, NB), NTHR, 0, stream>>>(r, z, grid, out);
}

// Round 3
// 78.689 us; speedup vs baseline: 1.0236x; 1.0026x over previous
//
#include <hip/hip_runtime.h>

#define NB     32
#define NATOM  48
#define NGRID  128
#define KT     8                          /* grid points per block */
#define NTHR   768                        /* 12 waves: thread = (n, kk, h) */

#define MBTR_ELEMS (NB*16*NGRID)          /* 65536 */
#define DIV_PER_B  (16*NGRID*NATOM*3)     /* 294912 */
#define PANE       (NGRID*NATOM*3)        /* 18432 floats per (e1,e2) pane */
#define MSTRIDE    49                     /* padded n-stride for M table */

// R10: BARRIER REORDER. R9 post-mortem: occupancy 12->24 waves/CU + half
// phase-1 depth bought only 1.6us => phase-1 latency NOT dominant. New
// theory: the old order (div stores -> __syncthreads -> 2b) makes every
// wave stall at the barrier's implicit s_waitcnt vmcnt(0) until the block's
// ~147KB of div stores drain to L2 (~10us/CU at HBM share); both resident
// blocks stall on the same drain, which is exactly why extra occupancy
// didn't help. Fix: phase1 -> Mrec(LDS) -> barrier (only lgkm outstanding)
// -> 2b mbtr reduction -> div stores LAST, no barrier after; stores drain
// asynchronously into kernel-end retirement.
// Everything else identical to harness-verified R9 (species-sorted inner
// loop, h-split ownership rule, register-direct div stores).
__global__ __launch_bounds__(NTHR, 6)
void mbtr_fused(const float* __restrict__ r, const int* __restrict__ z,
                const float* __restrict__ grid, float* __restrict__ out)
{
    const int kt = blockIdx.x, b = blockIdx.y, t = threadIdx.x;
    const int k0 = kt * KT;

    __shared__ float4 pos_s[NATOM + 1];   /* species-sorted; +1 prefetch pad */
    __shared__ int    zl[NATOM];
    __shared__ int    soff_s[5];
    __shared__ float  znpos[NATOM * 3];   /* unsorted positions for rn */
    __shared__ float  Mrec[KT * 4 * MSTRIDE];   /* [kk][e][49] */

    // ---- setup: wave 0 loads atoms, scatters them species-sorted ----
    if (t < 64) {
        const bool isatom = (t < NATOM);
        int myz = 999;
        float rx = 0.f, ry = 0.f, rz = 0.f;
        if (isatom) {
            myz = z[t];
            zl[t] = myz;
            const float* rp = r + ((size_t)b * NATOM + t) * 3;
            rx = rp[0]; ry = rp[1]; rz = rp[2];
            znpos[t * 3 + 0] = rx; znpos[t * 3 + 1] = ry; znpos[t * 3 + 2] = rz;
        }
        const unsigned long long m0 = __ballot(myz == 0);
        const unsigned long long m1 = __ballot(myz == 1);
        const unsigned long long m2 = __ballot(myz == 2);
        const unsigned long long m3 = __ballot(myz == 3);
        const int c0 = __popcll(m0), c1 = __popcll(m1), c2 = __popcll(m2);
        if (isatom) {
            const unsigned long long mm = (myz == 0) ? m0 : (myz == 1) ? m1
                                        : (myz == 2) ? m2 : m3;
            const int base = (myz == 0) ? 0 : (myz == 1) ? c0
                           : (myz == 2) ? c0 + c1 : c0 + c1 + c2;
            const int rank = __popcll(mm & ((1ull << t) - 1ull));
            pos_s[base + rank] = make_float4(rx, ry, rz, (float)t);
        }
        if (t == 0) {
            soff_s[0] = 0; soff_s[1] = c0; soff_s[2] = c0 + c1;
            soff_s[3] = c0 + c1 + c2; soff_s[4] = NATOM;
            pos_s[NATOM] = make_float4(0.f, 0.f, 0.f, -1.f);  // prefetch pad
        }
    }
    __syncthreads();

    // ---- phase 1: thread = (n, kk, h); h owns species {2h, 2h+1} ----
    const int n  = t % NATOM;
    const int kk = (t / NATOM) & (KT - 1);  // 0..7
    const int h  = t / (NATOM * KT);        // 0 or 1
    const float dx   = grid[1] - grid[0];
    const float coef = dx * 7.9788456080286535f;     // dx*20/sqrt(2pi)
    const float mlc  = -__log2f(coef);
    const float isc  = 16.986436005760382f;          // 20*sqrt(log2e/2)
    const float tBc  = 23.548200452219559f;          // 20/sqrt(log2e/2)
    const float l2e  = 1.4426950408889634f;
    const float gk   = grid[k0 + kk] * isc;
    const float nf   = (float)n;

    float A[2][3] = {{0.f}};
    float M[2]    = {0.f, 0.f};
    const float rnx = znpos[n * 3 + 0];
    const float rny = znpos[n * 3 + 1];
    const float rnz = znpos[n * 3 + 2];
    const int   zn  = zl[n];
    const int so0 = soff_s[2 * h];
    const int so1 = soff_s[2 * h + 1];
    const int so2 = soff_s[2 * h + 2];

#define SEG_LOOP(LO, HI, J)                                                 \
    _Pragma("unroll 4")                                                     \
    for (int i = (LO); i < (HI); ++i) {                                     \
        const float4 rm = pos_s[i];     /* static-address broadcast read */ \
        const float ddx = rnx - rm.x, ddy = rny - rm.y, ddz = rnz - rm.z;   \
        float d2 = ddx*ddx + ddy*ddy + ddz*ddz;                             \
        const bool self = (rm.w == nf);                                     \
        d2 = self ? 1.0f : d2;                        /* rsq NaN guard */   \
        const float gf  = __builtin_amdgcn_rsqf(d2);  /* 1/d */             \
        const float c1  = gf * isc;                                         \
        const float d   = d2 * gf;                                          \
        float base = fmaf(d, l2e, mlc);               /* wf & coef folded */\
        base = self ? 1e30f : base;                   /* kill self pair */  \
        const float bq  = (gf * gf) * tBc;                                  \
        const float tt  = gk - c1;                                          \
        const float ex  = exp2f(-fmaf(tt, tt, base)); /* coef*wf*gv */      \
        M[J] += ex;                                                         \
        const float p   = ex * fmaf(tt, bq, 1.0f);                          \
        A[J][0] = fmaf(-p, gf * ddx, A[J][0]);                              \
        A[J][1] = fmaf(-p, gf * ddy, A[J][1]);                              \
        A[J][2] = fmaf(-p, gf * ddz, A[J][2]);                              \
    }

    SEG_LOOP(so0, so1, 0)
    SEG_LOOP(so1, so2, 1)
#undef SEG_LOOP

    {   // M table to LDS: this half's two element rows
        float* mr = Mrec + kk * (4 * MSTRIDE) + n;
        mr[(2 * h + 0) * MSTRIDE] = M[0];
        mr[(2 * h + 1) * MSTRIDE] = M[1];
    }

    // ---- barrier BEFORE any global stores: only LDS writes outstanding ----
    __syncthreads();

    // ---- phase 2b: mbtr reduction (threads 0..127: one (pane,kk) each) ----
    if (t < 128) {
        const int mpane = t >> 3, mkk = t & 7;
        const int me1 = mpane >> 2, me2 = mpane & 3;
        const float* tr2 = Mrec + mkk * (4 * MSTRIDE) + me2 * MSTRIDE;
        float s = 0.f;
        #pragma unroll
        for (int nn = 0; nn < NATOM; ++nn)
            s += (zl[nn] == me1) ? tr2[nn] : 0.f;
        out[(size_t)b * 2048 + mpane * NGRID + k0 + mkk] = s;
    }

    // ---- phase 2a LAST: div stores straight from registers (owner rule),
    //      no barrier after -> drain overlaps wave retirement ----
    float* basep = out + MBTR_ELEMS + (size_t)b * DIV_PER_B
                 + (size_t)(k0 + kk) * 144 + n * 3;
    #pragma unroll
    for (int e1 = 0; e1 < 4; ++e1) {
        #pragma unroll
        for (int e2 = 0; e2 < 4; ++e2) {
            float3 v; bool w;
            if (e1 == e2) {
                w = ((e1 >> 1) == h);
                const bool s = (zn == e1);
                v.x = s ? 2.f * A[e1 & 1][0] : 0.f;
                v.y = s ? 2.f * A[e1 & 1][1] : 0.f;
                v.z = s ? 2.f * A[e1 & 1][2] : 0.f;
            } else {
                const bool o2 = ((e2 >> 1) == h) & (zn == e1); // -> A[e2]
                const bool o1 = ((e1 >> 1) == h) & (zn == e2); // -> A[e1]
                const bool oz = (h == 0) & (zn != e1) & (zn != e2);
                w = o2 | o1 | oz;
                v.x = o2 ? A[e2 & 1][0] : (o1 ? A[e1 & 1][0] : 0.f);
                v.y = o2 ? A[e2 & 1][1] : (o1 ? A[e1 & 1][1] : 0.f);
                v.z = o2 ? A[e2 & 1][2] : (o1 ? A[e1 & 1][2] : 0.f);
            }
            if (w)
                *(float3*)(basep + (e1 * 4 + e2) * PANE) = v;
        }
    }
}

extern "C" void kernel_launch(void* const* d_in, const int* in_sizes, int n_in,
                              void* d_out, int out_size, void* d_ws, size_t ws_size,
                              hipStream_t stream)
{
    const float* r    = (const float*)d_in[0];
    const int*   z    = (const int*)  d_in[1];
    const float* grid = (const float*)d_in[2];
    float* out = (float*)d_out;
    (void)d_ws; (void)ws_size;

    mbtr_fused<<<dim3(NGRID / KT, NB), NTHR, 0, stream>>>(r, z, grid, out);
}